// Round 8
// baseline (166.382 us; speedup 1.0000x reference)
//
#include <hip/hip_runtime.h>
#include <math.h>

#define BB 4096
#define PP 512
#define WDT 10

typedef float float2v __attribute__((ext_vector_type(2)));

#define PKFMA(a, b, c) __builtin_elementwise_fma(a, b, c)
#define PKMAX(a, b)    __builtin_elementwise_max(a, b)
#define FENCE()        __builtin_amdgcn_sched_barrier(0)

__device__ __forceinline__ float2v bc2(float s) { return (float2v){s, s}; }

// tanh(x) = 1 - 2/(exp2(2*log2e*x)+1); inf-safe without clamps.
__device__ __forceinline__ float fast_tanh(float x) {
    float e = __builtin_amdgcn_exp2f(x * 2.8853900817779268f); // v_exp_f32
    return 1.0f - 2.0f * __builtin_amdgcn_rcpf(e + 1.0f);      // v_rcp_f32
}

// Weights are wave-uniform with compile-time offsets -> s_load into SGPRs.
// Uniform working set is PHASED (k-row halves, <=60 weight floats live) with
// sched_barrier(0) fences so the compiler never spills SGPRs (R1/R3 lesson).
// 2 pairs per thread: each phase's s_load stream + fence stall serves 2x the
// arithmetic, and the two independent chains double ILP through the
// trans-latency norm sections (R7 lesson: 36% idle at 1 pair/thread).
__global__ __launch_bounds__(256) void frc_2b_kernel(
    const float* __restrict__ invar,    // [B,P,5]
    const float* __restrict__ vectors,  // [B,P,9]
    const float* __restrict__ w1_0,     // [5,10]
    const float* __restrict__ b1_0,     // [10]
    const float* __restrict__ w1_1,     // [10,10]
    const float* __restrict__ b1_1,     // [10]
    const float* __restrict__ lin0_w,   // [3,10]
    const float* __restrict__ na0_b,    // [10]
    const float* __restrict__ lin1_w,   // [10,10]
    const float* __restrict__ na1_b,    // [10]
    const float* __restrict__ final_w,  // [10,1]
    float* __restrict__ out)            // [B,3]
{
    __shared__ float red[4][3];

    const int b   = blockIdx.x;
    const int tid = threadIdx.x;

    // ---- per-lane inputs for both pairs (issued first; latency hides under s_loads)
    const float* iv0 = invar   + ((size_t)b * PP + tid) * 5;
    const float* vv0 = vectors + ((size_t)b * PP + tid) * 9;
    float in5a[2][5];
    float v[2][9];
    #pragma unroll
    for (int i = 0; i < 5; ++i) { in5a[0][i] = iv0[i]; in5a[1][i] = iv0[256 * 5 + i]; }
    #pragma unroll
    for (int i = 0; i < 9; ++i) { v[0][i] = vv0[i]; v[1][i] = vv0[256 * 9 + i]; }

    const float k3sq  = 0.33333333333333333f;   // (1/sqrt3)^2
    const float k3k10 = 0.18257418583505536f;   // 1/sqrt(30)
    const float k10   = 0.31622776601683794f;   // 1/sqrt(10)
    const float2v z2  = {0.f, 0.f};

    // ================= Phase 1: L1  y = relu(in5 @ w1_0 + b1_0)
    float2v yp[2][5];
    #pragma unroll
    for (int jp = 0; jp < 5; ++jp) {
        float2v bb = *(const float2v*)(b1_0 + 2 * jp);
        yp[0][jp] = bb; yp[1][jp] = bb;
    }
    #pragma unroll
    for (int i = 0; i < 5; ++i) {
        #pragma unroll
        for (int jp = 0; jp < 5; ++jp) {
            float2v wp = *(const float2v*)(w1_0 + i * WDT + 2 * jp);
            yp[0][jp] = PKFMA(wp, bc2(in5a[0][i]), yp[0][jp]);
            yp[1][jp] = PKFMA(wp, bc2(in5a[1][i]), yp[1][jp]);
        }
    }
    #pragma unroll
    for (int pr = 0; pr < 2; ++pr)
        #pragma unroll
        for (int jp = 0; jp < 5; ++jp) yp[pr][jp] = PKMAX(yp[pr][jp], z2);
    FENCE();

    // ================= Phase 2: L2  y2 = relu(y @ w1_1 + b1_1), k-halves
    float2v y2p[2][5];
    #pragma unroll
    for (int jp = 0; jp < 5; ++jp) {
        float2v bb = *(const float2v*)(b1_1 + 2 * jp);
        y2p[0][jp] = bb; y2p[1][jp] = bb;
    }
    #pragma unroll
    for (int k = 0; k < 5; ++k) {
        #pragma unroll
        for (int jp = 0; jp < 5; ++jp) {
            float2v wp = *(const float2v*)(w1_1 + k * WDT + 2 * jp);
            y2p[0][jp] = PKFMA(wp, bc2(yp[0][k >> 1][k & 1]), y2p[0][jp]);
            y2p[1][jp] = PKFMA(wp, bc2(yp[1][k >> 1][k & 1]), y2p[1][jp]);
        }
    }
    FENCE();
    #pragma unroll
    for (int k = 5; k < WDT; ++k) {
        #pragma unroll
        for (int jp = 0; jp < 5; ++jp) {
            float2v wp = *(const float2v*)(w1_1 + k * WDT + 2 * jp);
            y2p[0][jp] = PKFMA(wp, bc2(yp[0][k >> 1][k & 1]), y2p[0][jp]);
            y2p[1][jp] = PKFMA(wp, bc2(yp[1][k >> 1][k & 1]), y2p[1][jp]);
        }
    }
    #pragma unroll
    for (int pr = 0; pr < 2; ++pr)
        #pragma unroll
        for (int jp = 0; jp < 5; ++jp) y2p[pr][jp] = PKMAX(y2p[pr][jp], z2);
    FENCE();

    // ================= Phase 3: lin0 + NormActivation
    float2v c0p[2][5], c1p[2][5], c2p[2][5];
    #pragma unroll
    for (int pr = 0; pr < 2; ++pr)
        #pragma unroll
        for (int jp = 0; jp < 5; ++jp) { c0p[pr][jp] = z2; c1p[pr][jp] = z2; c2p[pr][jp] = z2; }
    #pragma unroll
    for (int u = 0; u < 3; ++u) {
        #pragma unroll
        for (int jp = 0; jp < 5; ++jp) {
            float2v wp = *(const float2v*)(lin0_w + u * WDT + 2 * jp);
            #pragma unroll
            for (int pr = 0; pr < 2; ++pr) {
                c0p[pr][jp] = PKFMA(wp, bc2(v[pr][u * 3 + 0]), c0p[pr][jp]);
                c1p[pr][jp] = PKFMA(wp, bc2(v[pr][u * 3 + 1]), c1p[pr][jp]);
                c2p[pr][jp] = PKFMA(wp, bc2(v[pr][u * 3 + 2]), c2p[pr][jp]);
            }
        }
    }
    // x0 stored with 1/sqrt(30) folded in
    float2v x0p[2][5], x1p[2][5], x2p[2][5];
    #pragma unroll
    for (int jp = 0; jp < 5; ++jp) {
        float2v nab = *(const float2v*)(na0_b + 2 * jp);
        #pragma unroll
        for (int pr = 0; pr < 2; ++pr) {
            float2v n2p = PKFMA(c0p[pr][jp], c0p[pr][jp],
                          PKFMA(c1p[pr][jp], c1p[pr][jp], c2p[pr][jp] * c2p[pr][jp]));
            float2v mp  = PKMAX(n2p * bc2(k3sq), bc2(1e-12f));
            float fh[2];
            #pragma unroll
            for (int h = 0; h < 2; ++h) {
                float m     = mp[h];
                float inv_n = __builtin_amdgcn_rsqf(m);
                float n     = m * inv_n;
                float t     = fast_tanh(n + nab[h]);
                fh[h] = t * inv_n * k3k10;
            }
            float2v fp = {fh[0], fh[1]};
            x0p[pr][jp] = c0p[pr][jp] * fp;
            x1p[pr][jp] = c1p[pr][jp] * fp;
            x2p[pr][jp] = c2p[pr][jp] * fp;
        }
    }
    FENCE();

    // ================= Phase 4: lin1 (k-halves) + NormActivation + gate + final
    float2v e0p[2][5], e1p[2][5], e2p[2][5];
    #pragma unroll
    for (int pr = 0; pr < 2; ++pr)
        #pragma unroll
        for (int jp = 0; jp < 5; ++jp) { e0p[pr][jp] = z2; e1p[pr][jp] = z2; e2p[pr][jp] = z2; }
    #pragma unroll
    for (int u = 0; u < 5; ++u) {
        #pragma unroll
        for (int jp = 0; jp < 5; ++jp) {
            float2v wp = *(const float2v*)(lin1_w + u * WDT + 2 * jp);
            #pragma unroll
            for (int pr = 0; pr < 2; ++pr) {
                e0p[pr][jp] = PKFMA(wp, bc2(x0p[pr][u >> 1][u & 1]), e0p[pr][jp]);
                e1p[pr][jp] = PKFMA(wp, bc2(x1p[pr][u >> 1][u & 1]), e1p[pr][jp]);
                e2p[pr][jp] = PKFMA(wp, bc2(x2p[pr][u >> 1][u & 1]), e2p[pr][jp]);
            }
        }
    }
    FENCE();
    #pragma unroll
    for (int u = 5; u < WDT; ++u) {
        #pragma unroll
        for (int jp = 0; jp < 5; ++jp) {
            float2v wp = *(const float2v*)(lin1_w + u * WDT + 2 * jp);
            #pragma unroll
            for (int pr = 0; pr < 2; ++pr) {
                e0p[pr][jp] = PKFMA(wp, bc2(x0p[pr][u >> 1][u & 1]), e0p[pr][jp]);
                e1p[pr][jp] = PKFMA(wp, bc2(x1p[pr][u >> 1][u & 1]), e1p[pr][jp]);
                e2p[pr][jp] = PKFMA(wp, bc2(x2p[pr][u >> 1][u & 1]), e2p[pr][jp]);
            }
        }
    }
    FENCE();

    float2v a0p = z2, a1p = z2, a2p = z2;
    #pragma unroll
    for (int jp = 0; jp < 5; ++jp) {
        float2v nab = *(const float2v*)(na1_b + 2 * jp);
        float2v fwp = *(const float2v*)(final_w + 2 * jp);
        #pragma unroll
        for (int pr = 0; pr < 2; ++pr) {
            // e == reference y2v (scales folded upstream)
            float2v n2p = PKFMA(e0p[pr][jp], e0p[pr][jp],
                          PKFMA(e1p[pr][jp], e1p[pr][jp], e2p[pr][jp] * e2p[pr][jp]));
            float2v mp  = PKMAX(n2p, bc2(1e-12f));
            float gh[2];
            #pragma unroll
            for (int h = 0; h < 2; ++h) {
                float m     = mp[h];
                float inv_n = __builtin_amdgcn_rsqf(m);
                float n     = m * inv_n;
                float t     = fast_tanh(n + nab[h]);
                gh[h] = y2p[pr][jp][h] * t * inv_n * fwp[h];
            }
            float2v gp = {gh[0], gh[1]};
            a0p = PKFMA(e0p[pr][jp], gp, a0p);
            a1p = PKFMA(e1p[pr][jp], gp, a1p);
            a2p = PKFMA(e2p[pr][jp], gp, a2p);
        }
    }
    // final 1/sqrt(10) pulled out of the j-sum (linear)
    float acc0 = (a0p[0] + a0p[1]) * k10;
    float acc1 = (a1p[0] + a1p[1]) * k10;
    float acc2 = (a2p[0] + a2p[1]) * k10;

    // ---- reduce 256 threads (512 pairs) -> out[b][0..2]
    #pragma unroll
    for (int off = 32; off > 0; off >>= 1) {
        acc0 += __shfl_down(acc0, off, 64);
        acc1 += __shfl_down(acc1, off, 64);
        acc2 += __shfl_down(acc2, off, 64);
    }
    const int wave = tid >> 6;
    if ((tid & 63) == 0) { red[wave][0] = acc0; red[wave][1] = acc1; red[wave][2] = acc2; }
    __syncthreads();
    if (tid == 0) {
        float r0 = 0.f, r1 = 0.f, r2 = 0.f;
        #pragma unroll
        for (int wv = 0; wv < 4; ++wv) { r0 += red[wv][0]; r1 += red[wv][1]; r2 += red[wv][2]; }
        out[b * 3 + 0] = r0;
        out[b * 3 + 1] = r1;
        out[b * 3 + 2] = r2;
    }
}

extern "C" void kernel_launch(void* const* d_in, const int* in_sizes, int n_in,
                              void* d_out, int out_size, void* d_ws, size_t ws_size,
                              hipStream_t stream) {
    const float* invar   = (const float*)d_in[0];
    const float* vectors = (const float*)d_in[1];
    const float* w1_0    = (const float*)d_in[2];
    const float* b1_0    = (const float*)d_in[3];
    const float* w1_1    = (const float*)d_in[4];
    const float* b1_1    = (const float*)d_in[5];
    const float* lin0_w  = (const float*)d_in[6];
    const float* na0_b   = (const float*)d_in[7];
    const float* lin1_w  = (const float*)d_in[8];
    const float* na1_b   = (const float*)d_in[9];
    const float* final_w = (const float*)d_in[10];
    float* out = (float*)d_out;

    frc_2b_kernel<<<BB, 256, 0, stream>>>(invar, vectors, w1_0, b1_0, w1_1, b1_1,
                                          lin0_w, na0_b, lin1_w, na1_b, final_w, out);
}